// Round 8
// baseline (203.541 us; speedup 1.0000x reference)
//
#include <hip/hip_runtime.h>
#include <hip/hip_bf16.h>
#include <stdint.h>

#define D_MODEL 1024
#define NH 16
#define HD 64
#define SEQ 2048
#define BATCH 2
#define ROWS (BATCH * SEQ)   // 4096
#define KDIM 1024
#define NQKV 3072

typedef unsigned short u16;
typedef short bf16x8 __attribute__((ext_vector_type(8)));   // 8 bf16 in 4 VGPRs
typedef short bf16x4 __attribute__((ext_vector_type(4)));   // 4 bf16 in 2 VGPRs
typedef float f32x4 __attribute__((ext_vector_type(4)));

__device__ __forceinline__ u16 f2bf(float f) {
  union { float f; unsigned u; } x; x.f = f;
  unsigned r = x.u + 0x7fff + ((x.u >> 16) & 1);   // RNE
  return (u16)(r >> 16);
}

// packed RNE f32x2 -> bf16x2 (v_cvt_pk_bf16_f32 on gfx950)
__device__ __forceinline__ bf16x4 pack4(float a, float b, float c, float d) {
  union { __hip_bfloat162 h2[2]; bf16x4 v; } u;
  u.h2[0] = __float22bfloat162_rn(make_float2(a, b));
  u.h2[1] = __float22bfloat162_rn(make_float2(c, d));
  return u.v;
}
__device__ __forceinline__ ushort4 packu4(float a, float b, float c, float d) {
  union { __hip_bfloat162 h2[2]; ushort4 v; } u;
  u.h2[0] = __float22bfloat162_rn(make_float2(a, b));
  u.h2[1] = __float22bfloat162_rn(make_float2(c, d));
  return u.v;
}

#ifndef HAVE_MFMA16_1K
#if defined(__has_builtin)
#if __has_builtin(__builtin_amdgcn_mfma_f32_16x16x16bf16_1k)
#define HAVE_MFMA16_1K 1
#endif
#endif
#endif
__device__ __forceinline__ f32x4 mfma16(bf16x4 a, bf16x4 b, f32x4 c) {
#ifdef HAVE_MFMA16_1K
  return __builtin_amdgcn_mfma_f32_16x16x16bf16_1k(a, b, c, 0, 0, 0);
#else
  bf16x8 a8 = {a[0], a[1], a[2], a[3], 0, 0, 0, 0};
  bf16x8 b8 = {b[0], b[1], b[2], b[3], 0, 0, 0, 0};
  return __builtin_amdgcn_mfma_f32_16x16x32_bf16(a8, b8, c, 0, 0, 0);
#endif
}

// async global->LDS, 16B/lane. LDS dst is wave-uniform base + lane*16;
// global SOURCE address is per-lane arbitrary (16B contiguous) -> swizzle there.
__device__ __forceinline__ void gload16(const u16* g, u16* l) {
  __builtin_amdgcn_global_load_lds(
      (const __attribute__((address_space(1))) unsigned int*)g,
      (__attribute__((address_space(3))) unsigned int*)l, 16, 0, 0);
}

// ---- fused prep: query cvt, weight transposes, rope table [f][s] ----
__global__ void prep_kernel(const float* __restrict__ query, u16* __restrict__ q_bf,
                            const float* __restrict__ W_qkv, u16* __restrict__ wt_qkv,
                            const float* __restrict__ W_out, u16* __restrict__ wt_out,
                            float2* __restrict__ rope_tab) {
  __shared__ float tile[32][33];
  const int blk = blockIdx.x, tid = threadIdx.x;
  if (blk < 4096) {                       // query fp32 -> bf16
    int i = blk * 256 + tid;
    float4 v = ((const float4*)query)[i];
    ushort4 o;
    o.x = f2bf(v.x); o.y = f2bf(v.y); o.z = f2bf(v.z); o.w = f2bf(v.w);
    ((ushort4*)q_bf)[i] = o;
  } else if (blk < 8192) {                // W transpose+convert (32x32 tiles)
    const float* W; u16* Wt; int N, t;
    if (blk < 7168) { W = W_qkv; Wt = wt_qkv; N = NQKV; t = blk - 4096; }
    else            { W = W_out; Wt = wt_out; N = D_MODEL; t = blk - 7168; }
    int nb = N / 32;
    int c0 = (t % nb) * 32, r0 = (t / nb) * 32;
    int tx = tid & 31, ty = tid >> 5;
    for (int i = ty; i < 32; i += 8)
      tile[i][tx] = W[(size_t)(r0 + i) * N + c0 + tx];
    __syncthreads();
    for (int i = ty; i < 32; i += 8)
      Wt[(size_t)(c0 + i) * KDIM + r0 + tx] = f2bf(tile[tx][i]);
  } else {                                // rope table: tab[f*2048+s] = (cos, sin)
    int i = (blk - 8192) * 256 + tid;     // 65536 entries
    int f = i >> 11, s = i & 2047;
    float inv = __expf(-(float)f * 0.28782313662425572f);  // ln(1e4)/32
    float ang = (float)s * inv;
    rope_tab[i] = make_float2(cosf(ang), sinf(ang));
  }
}

// ---------------- QKV GEMM + bias + RoPE + packed-store scatter ----------------
// LDS XOR-swizzled staging (zero bank conflicts, verified R7).
// q/k waves SWAP MFMA operands: C-layout becomes lane&15<->s, quad*4+r<->channel,
// so each lane holds 4 consecutive hd at fixed s -> packed 8B stores, no LDS
// transpose. V waves keep original order (4 consecutive s at fixed hd for v^T).
// outputs PLAIN layouts: qb/kb[bh][s][hd], vtb[bh][hd][s]. q pre-scaled by kS.
__global__ __launch_bounds__(256) void qkv_gemm_kernel(
    const u16* __restrict__ A, const u16* __restrict__ Bt, const float* __restrict__ bias,
    const float2* __restrict__ rope_tab,
    u16* __restrict__ qb, u16* __restrict__ kb, u16* __restrict__ vtb) {
  __shared__ u16 As[8192];
  __shared__ u16 Bs[8192];
  const int tid = threadIdx.x;
  const int lane = tid & 63, wave = tid >> 6;
  const int wr = (wave >> 1) << 6, wc = (wave & 1) << 6;
  const int lrow = lane & 15, quad = lane >> 4;
  const int sw = lrow & 7;
  const int rowA0 = blockIdx.y * 128, rowB0 = blockIdx.x * 128;

  const int col0 = rowB0 + wc;           // 64-aligned -> one head-slab per wave
  const int which = col0 >> 10;          // 0=q 1=k 2=v (wave-uniform)
  const bool isqk = (which < 2);

  f32x4 acc[4][4] = {};

  for (int k0 = 0; k0 < KDIM; k0 += 64) {
    __syncthreads();
#pragma unroll
    for (int it = 0; it < 4; ++it) {
      int flat = it * 256 + tid;
      int r = flat >> 3, cs = ((flat & 7) ^ (r & 7)) << 3;   // source swizzle
      gload16(A + (size_t)(rowA0 + r) * KDIM + k0 + cs, As + flat * 8);
      gload16(Bt + (size_t)(rowB0 + r) * KDIM + k0 + cs, Bs + flat * 8);
    }
    __syncthreads();
#pragma unroll
    for (int kk = 0; kk < 64; kk += 32) {
      const int ch = ((kk >> 3) + quad) ^ sw;    // swizzled chunk, uniform per lane
      bf16x8 af[4], bfr[4];
#pragma unroll
      for (int mi = 0; mi < 4; ++mi)
        af[mi] = *(const bf16x8*)(As + (wr + mi * 16 + lrow) * 64 + (ch << 3));
#pragma unroll
      for (int ni = 0; ni < 4; ++ni)
        bfr[ni] = *(const bf16x8*)(Bs + (wc + ni * 16 + lrow) * 64 + (ch << 3));
      if (isqk) {    // swapped: lane&15 <-> A-row (s), quad*4+r <-> B-row (chan)
#pragma unroll
        for (int mi = 0; mi < 4; ++mi)
#pragma unroll
          for (int ni = 0; ni < 4; ++ni)
            acc[mi][ni] = __builtin_amdgcn_mfma_f32_16x16x32_bf16(bfr[ni], af[mi], acc[mi][ni], 0, 0, 0);
      } else {       // original: lane&15 <-> B-row (chan), quad*4+r <-> A-row (s)
#pragma unroll
        for (int mi = 0; mi < 4; ++mi)
#pragma unroll
          for (int ni = 0; ni < 4; ++ni)
            acc[mi][ni] = __builtin_amdgcn_mfma_f32_16x16x32_bf16(af[mi], bfr[ni], acc[mi][ni], 0, 0, 0);
      }
    }
  }

  const int h = (col0 & 1023) >> 6;
  const int b = rowA0 >> 11;
  const int sbase = (rowA0 & 2047) + wr; // slab rows all in batch b

  if (isqk) {
    // bias: channel = col0 + ni*16 + quad*4 + r -> coalesced float4
#pragma unroll
    for (int ni = 0; ni < 4; ++ni) {
      float4 bv = *(const float4*)&bias[col0 + ni * 16 + quad * 4];
#pragma unroll
      for (int mi = 0; mi < 4; ++mi) {
        acc[mi][ni][0] += bv.x; acc[mi][ni][1] += bv.y;
        acc[mi][ni][2] += bv.z; acc[mi][ni][3] += bv.w;
      }
    }
    // RoPE: pairs (hd, hd+32) = (ni=p, ni=p+2), same lane & r. Table [f][s].
    const float qs = (which == 0) ? 0.18033688011112042f : 1.0f;
#pragma unroll
    for (int p = 0; p < 2; ++p) {
#pragma unroll
      for (int r = 0; r < 4; ++r) {
        const float2* tb = rope_tab + (size_t)(p * 16 + quad * 4 + r) * 2048;
#pragma unroll
        for (int mi = 0; mi < 4; ++mi) {
          float2 cs = tb[sbase + mi * 16 + lrow];   // 16 lanes consecutive s
          float x1 = acc[mi][p][r], x2 = acc[mi][p + 2][r];
          acc[mi][p][r]     = (x1 * cs.x - x2 * cs.y) * qs;
          acc[mi][p + 2][r] = (x2 * cs.x + x1 * cs.y) * qs;
        }
      }
    }
    // packed 8B stores: lane writes 4 consecutive hd at fixed s
    u16* dst = ((which == 0) ? qb : kb) + (size_t)(b * NH + h) * SEQ * HD;
#pragma unroll
    for (int mi = 0; mi < 4; ++mi) {
      size_t srow = (size_t)(sbase + mi * 16 + lrow) * HD + quad * 4;
#pragma unroll
      for (int ni = 0; ni < 4; ++ni) {
        ushort4 pk = packu4(acc[mi][ni][0], acc[mi][ni][1], acc[mi][ni][2], acc[mi][ni][3]);
        *(ushort4*)(dst + srow + ni * 16) = pk;
      }
    }
  } else {
    // V^T: original C-layout, r-quad = 4 consecutive s at fixed hd -> 8B stores
#pragma unroll
    for (int ni = 0; ni < 4; ++ni) {
      float bv = bias[col0 + ni * 16 + lrow];
#pragma unroll
      for (int mi = 0; mi < 4; ++mi)
#pragma unroll
        for (int r = 0; r < 4; ++r) acc[mi][ni][r] += bv;
    }
    u16* dst = vtb + (size_t)(b * NH + h) * HD * SEQ;
#pragma unroll
    for (int ni = 0; ni < 4; ++ni) {
      int hd = ni * 16 + lrow;
#pragma unroll
      for (int mi = 0; mi < 4; ++mi) {
        ushort4 pk = packu4(acc[mi][ni][0], acc[mi][ni][1], acc[mi][ni][2], acc[mi][ni][3]);
        *(ushort4*)(dst + (size_t)hd * SEQ + sbase + mi * 16 + quad * 4) = pk;
      }
    }
  }
}

// ---------------- causal flash attention v7: 128q x 128k, CU-balanced ------
// 512 blocks; id->tile mapping pairs heavy+light on each CU (t1+t2=15 ->
// exactly 17 iterations per CU with 2 blocks/CU round-robin). Wave owns 32 q
// (groups lrow, lrow+16); K/V fragments read once feed both groups. Fixed-offset
// softmax (-12 folded into MFMA C-init; cancels in O = sum(p v)/sum(p)).
__global__ __launch_bounds__(256, 2) void flash_kernel(
    const u16* __restrict__ qb, const u16* __restrict__ kb,
    const u16* __restrict__ vtb, u16* __restrict__ attnb) {
  __shared__ u16 Ks[2][128 * 64];      // 32 KB (key-major, chunk^row swizzle)
  __shared__ u16 Vts[2][64 * 128];     // 32 KB (hd-major,  chunk^row swizzle)

  const int tid = threadIdx.x, lane = tid & 63, wave = tid >> 6;
  const int lrow = lane & 15, quad = lane >> 4;
  const int id = blockIdx.x;
  // CU-balance: first 256 blocks t=15..8 (heavy), last 256 t=0..7 -> pair sum 15
  const int t = (id < 256) ? (15 - (id >> 5)) : ((id >> 5) - 8);
  const int bh = id & 31;
  const int b = bh >> 4, h = bh & 15;

  const u16* qp = qb + (size_t)bh * SEQ * HD;
  const u16* kp = kb + (size_t)bh * SEQ * HD;
  const u16* vp = vtb + (size_t)bh * HD * SEQ;

  const int qa = t * 128 + wave * 32 + lrow;    // q-group a
  const int qg2 = qa + 16;                      // q-group b
  bf16x8 bqa[2], bqb[2];
#pragma unroll
  for (int hc = 0; hc < 2; ++hc) {
    bqa[hc] = *(const bf16x8*)(qp + (size_t)qa * HD + hc * 32 + quad * 8);
    bqb[hc] = *(const bf16x8*)(qp + (size_t)qg2 * HD + hc * 32 + quad * 8);
  }

#pragma unroll
  for (int it = 0; it < 4; ++it) {     // stage K/V tile 0 into buf 0
    int f = it * 256 + tid;
    int rk = f >> 3, ck = f & 7;
    gload16(kp + (size_t)rk * HD + ((ck ^ (rk & 7)) << 3), Ks[0] + f * 8);
    int rv = f >> 4, cv = f & 15;
    gload16(vp + (size_t)rv * SEQ + ((cv ^ (rv & 7)) << 3), Vts[0] + f * 8);
  }

  f32x4 oa[4] = {}, ob[4] = {};
  f32x4 la = {}, lb = {};
  const int sw = lrow & 7;

  for (int kt = 0; kt <= t; ++kt) {
    const int cur = kt & 1, nxt = cur ^ 1;
    __syncthreads();                   // drains cur staging; guards LDS reuse
    if (kt < t) {                      // async prefetch next 128-key tile
#pragma unroll
      for (int it = 0; it < 4; ++it) {
        int f = it * 256 + tid;
        int rk = f >> 3, ck = f & 7;
        gload16(kp + (size_t)((kt + 1) * 128 + rk) * HD + ((ck ^ (rk & 7)) << 3),
                Ks[nxt] + f * 8);
        int rv = f >> 4, cv = f & 15;
        gload16(vp + (size_t)rv * SEQ + (kt + 1) * 128 + ((cv ^ (rv & 7)) << 3),
                Vts[nxt] + f * 8);
      }
    }

    // S^T = K.Q^T, C-init = -12 (exp2 offset). Shared ak feeds both q-groups.
    f32x4 sa[8], sb[8];
#pragma unroll
    for (int ki = 0; ki < 8; ++ki) { sa[ki] = -12.f; sb[ki] = -12.f; }
#pragma unroll
    for (int hc = 0; hc < 2; ++hc) {
      bf16x8 ak[8];
#pragma unroll
      for (int ki = 0; ki < 8; ++ki)
        ak[ki] = *(const bf16x8*)(Ks[cur] + (ki * 16 + lrow) * 64 +
                                  (((hc * 4 + quad) ^ sw) << 3));
#pragma unroll
      for (int ki = 0; ki < 8; ++ki)
        sa[ki] = __builtin_amdgcn_mfma_f32_16x16x32_bf16(ak[ki], bqa[hc], sa[ki], 0, 0, 0);
#pragma unroll
      for (int ki = 0; ki < 8; ++ki)
        sb[ki] = __builtin_amdgcn_mfma_f32_16x16x32_bf16(ak[ki], bqb[hc], sb[ki], 0, 0, 0);
    }

    if (kt == t) {                     // causal mask (diagonal tile only)
#pragma unroll
      for (int ki = 0; ki < 8; ++ki)
#pragma unroll
        for (int r = 0; r < 4; ++r) {
          int key = kt * 128 + ki * 16 + quad * 4 + r;
          if (key > qa)  sa[ki][r] = -1e30f;
          if (key > qg2) sb[ki][r] = -1e30f;
        }
    }

    // exp2 (offset already applied) + vector denominator + packed P fragments
    bf16x4 pfa[8], pfb[8];
#pragma unroll
    for (int ki = 0; ki < 8; ++ki) {
#pragma unroll
      for (int r = 0; r < 4; ++r) { sa[ki][r] = exp2f(sa[ki][r]); sb[ki][r] = exp2f(sb[ki][r]); }
      la += sa[ki];
      lb += sb[ki];
      pfa[ki] = pack4(sa[ki][0], sa[ki][1], sa[ki][2], sa[ki][3]);
      pfb[ki] = pack4(sb[ki][0], sb[ki][1], sb[ki][2], sb[ki][3]);
    }

    // O^T += V^T.P^T — shared av feeds both q-groups
#pragma unroll
    for (int mi = 0; mi < 4; ++mi) {
      int vrow = (mi * 16 + lrow) * 128;
#pragma unroll
      for (int ki = 0; ki < 8; ++ki) {
        bf16x4 av = *(const bf16x4*)(Vts[cur] + vrow +
                                     ((((ki * 2 + (quad >> 1)) ^ sw) << 3) | ((quad & 1) << 2)));
        oa[mi] = mfma16(av, pfa[ki], oa[mi]);
        ob[mi] = mfma16(av, pfb[ki], ob[mi]);
      }
    }
  }

  // denominators: horizontal f32x4 sum, then cross-quad reduce
  float l_a = la[0] + la[1] + la[2] + la[3];
  float l_b = lb[0] + lb[1] + lb[2] + lb[3];
  l_a += __shfl_xor(l_a, 16); l_a += __shfl_xor(l_a, 32);
  l_b += __shfl_xor(l_b, 16); l_b += __shfl_xor(l_b, 32);
  float ra = 1.f / l_a, rb = 1.f / l_b;

  u16* opa = attnb + ((size_t)(b * SEQ + qa)) * D_MODEL + h * HD;
  u16* opb = attnb + ((size_t)(b * SEQ + qg2)) * D_MODEL + h * HD;
#pragma unroll
  for (int mi = 0; mi < 4; ++mi) {
    ushort4 pka = packu4(oa[mi][0] * ra, oa[mi][1] * ra, oa[mi][2] * ra, oa[mi][3] * ra);
    *(ushort4*)(opa + mi * 16 + quad * 4) = pka;
    ushort4 pkb = packu4(ob[mi][0] * rb, ob[mi][1] * rb, ob[mi][2] * rb, ob[mi][3] * rb);
    *(ushort4*)(opb + mi * 16 + quad * 4) = pkb;
  }
}

// -------- output projection: 128x64 tiles, swapped operands -> float4 stores ----
__global__ __launch_bounds__(256) void out_gemm_kernel(
    const u16* __restrict__ A, const u16* __restrict__ Bt, const float* __restrict__ bias,
    float* __restrict__ out) {
  __shared__ u16 As[128 * 64];
  __shared__ u16 Bs[64 * 64];
  const int tid = threadIdx.x;
  const int lane = tid & 63, wave = tid >> 6;
  const int lrow = lane & 15, quad = lane >> 4;
  const int sw = lrow & 7;
  const int wr = wave * 32;
  const int rowA0 = blockIdx.y * 128, colB0 = blockIdx.x * 64;

  f32x4 acc[2][4] = {};

  for (int k0 = 0; k0 < KDIM; k0 += 64) {
    __syncthreads();
#pragma unroll
    for (int it = 0; it < 4; ++it) {
      int f = it * 256 + tid;
      int r = f >> 3, cs = ((f & 7) ^ (r & 7)) << 3;
      gload16(A + (size_t)(rowA0 + r) * KDIM + k0 + cs, As + f * 8);
    }
#pragma unroll
    for (int it = 0; it < 2; ++it) {
      int f = it * 256 + tid;
      int r = f >> 3, cs = ((f & 7) ^ (r & 7)) << 3;
      gload16(Bt + (size_t)(colB0 + r) * KDIM + k0 + cs, Bs + f * 8);
    }
    __syncthreads();
#pragma unroll
    for (int kk = 0; kk < 64; kk += 32) {
      const int ch = ((kk >> 3) + quad) ^ sw;
      bf16x8 af[2], bfr[4];
#pragma unroll
      for (int mi = 0; mi < 2; ++mi)
        af[mi] = *(const bf16x8*)(As + (wr + mi * 16 + lrow) * 64 + (ch << 3));
#pragma unroll
      for (int ni = 0; ni < 4; ++ni)
        bfr[ni] = *(const bf16x8*)(Bs + (ni * 16 + lrow) * 64 + (ch << 3));
      // swapped operands: lane&15 <-> A-row (s), quad*4+r <-> B-row (col)
#pragma unroll
      for (int mi = 0; mi < 2; ++mi)
#pragma unroll
        for (int ni = 0; ni < 4; ++ni)
          acc[mi][ni] = __builtin_amdgcn_mfma_f32_16x16x32_bf16(bfr[ni], af[mi], acc[mi][ni], 0, 0, 0);
    }
  }

#pragma unroll
  for (int ni = 0; ni < 4; ++ni) {
    float4 bv = *(const float4*)&bias[colB0 + ni * 16 + quad * 4];
#pragma unroll
    for (int mi = 0; mi < 2; ++mi) {
      int row = rowA0 + wr + mi * 16 + lrow;
      float4 o4 = make_float4(acc[mi][ni][0] + bv.x, acc[mi][ni][1] + bv.y,
                              acc[mi][ni][2] + bv.z, acc[mi][ni][3] + bv.w);
      *(float4*)&out[(size_t)row * D_MODEL + colB0 + ni * 16 + quad * 4] = o4;
    }
  }
}

extern "C" void kernel_launch(void* const* d_in, const int* in_sizes, int n_in,
                              void* d_out, int out_size, void* d_ws, size_t ws_size,
                              hipStream_t stream) {
  const float* query = (const float*)d_in[0];
  const float* W_qkv = (const float*)d_in[1];
  const float* b_qkv = (const float*)d_in[2];
  const float* W_out = (const float*)d_in[3];
  const float* b_out = (const float*)d_in[4];
  float* out = (float*)d_out;

  char* ws = (char*)d_ws;
  u16* q_bf    = (u16*)(ws);                 //  8 MB  query bf16 (4096x1024)
  u16* wt_qkv  = (u16*)(ws + 8388608);       //  6 MB  W_qkv^T bf16
  u16* wt_out  = (u16*)(ws + 14680064);      //  2 MB  W_out^T bf16
  u16* qbuf    = (u16*)(ws + 16777216);      //  8 MB  q (bh,s,hd) plain, pre-scaled kS
  u16* kbuf    = (u16*)(ws + 25165824);      //  8 MB  k (bh,s,hd) plain
  u16* vtbuf   = (u16*)(ws + 33554432);      //  8 MB  v^T (bh,hd,s) plain
  u16* attnb   = (u16*)(ws + 41943040);      //  8 MB  attn (B,S,D) bf16
  float2* rope = (float2*)(ws + 50331648);   // 512 KB rope table [f][s]

  prep_kernel<<<dim3(8448), dim3(256), 0, stream>>>(query, q_bf, W_qkv, wt_qkv,
                                                    W_out, wt_out, rope);
  qkv_gemm_kernel<<<dim3(NQKV / 128, ROWS / 128), dim3(256), 0, stream>>>(
      q_bf, wt_qkv, b_qkv, rope, qbuf, kbuf, vtbuf);
  flash_kernel<<<dim3(512), dim3(256), 0, stream>>>(qbuf, kbuf, vtbuf, attnb);
  out_gemm_kernel<<<dim3(D_MODEL / 64, ROWS / 128), dim3(256), 0, stream>>>(
      attnb, wt_out, b_out, out);
}

// Round 9
// 191.912 us; speedup vs baseline: 1.0606x; 1.0606x over previous
//
#include <hip/hip_runtime.h>
#include <hip/hip_bf16.h>
#include <stdint.h>

#define D_MODEL 1024
#define NH 16
#define HD 64
#define SEQ 2048
#define BATCH 2
#define ROWS (BATCH * SEQ)   // 4096
#define KDIM 1024
#define NQKV 3072

typedef unsigned short u16;
typedef short bf16x8 __attribute__((ext_vector_type(8)));   // 8 bf16 in 4 VGPRs
typedef short bf16x4 __attribute__((ext_vector_type(4)));   // 4 bf16 in 2 VGPRs
typedef float f32x4 __attribute__((ext_vector_type(4)));

__device__ __forceinline__ u16 f2bf(float f) {
  union { float f; unsigned u; } x; x.f = f;
  unsigned r = x.u + 0x7fff + ((x.u >> 16) & 1);   // RNE
  return (u16)(r >> 16);
}

// packed RNE f32x2 -> bf16x2 (v_cvt_pk_bf16_f32 on gfx950)
__device__ __forceinline__ bf16x4 pack4(float a, float b, float c, float d) {
  union { __hip_bfloat162 h2[2]; bf16x4 v; } u;
  u.h2[0] = __float22bfloat162_rn(make_float2(a, b));
  u.h2[1] = __float22bfloat162_rn(make_float2(c, d));
  return u.v;
}
__device__ __forceinline__ ushort4 packu4(float a, float b, float c, float d) {
  union { __hip_bfloat162 h2[2]; ushort4 v; } u;
  u.h2[0] = __float22bfloat162_rn(make_float2(a, b));
  u.h2[1] = __float22bfloat162_rn(make_float2(c, d));
  return u.v;
}

#ifndef HAVE_MFMA16_1K
#if defined(__has_builtin)
#if __has_builtin(__builtin_amdgcn_mfma_f32_16x16x16bf16_1k)
#define HAVE_MFMA16_1K 1
#endif
#endif
#endif
__device__ __forceinline__ f32x4 mfma16(bf16x4 a, bf16x4 b, f32x4 c) {
#ifdef HAVE_MFMA16_1K
  return __builtin_amdgcn_mfma_f32_16x16x16bf16_1k(a, b, c, 0, 0, 0);
#else
  bf16x8 a8 = {a[0], a[1], a[2], a[3], 0, 0, 0, 0};
  bf16x8 b8 = {b[0], b[1], b[2], b[3], 0, 0, 0, 0};
  return __builtin_amdgcn_mfma_f32_16x16x32_bf16(a8, b8, c, 0, 0, 0);
#endif
}

// async global->LDS, 16B/lane. LDS dst is wave-uniform base + lane*16;
// global SOURCE address is per-lane arbitrary (16B contiguous) -> swizzle there.
__device__ __forceinline__ void gload16(const u16* g, u16* l) {
  __builtin_amdgcn_global_load_lds(
      (const __attribute__((address_space(1))) unsigned int*)g,
      (__attribute__((address_space(3))) unsigned int*)l, 16, 0, 0);
}

// ---- fused prep: query cvt, weight transposes, rope table [f][s] ----
__global__ void prep_kernel(const float* __restrict__ query, u16* __restrict__ q_bf,
                            const float* __restrict__ W_qkv, u16* __restrict__ wt_qkv,
                            const float* __restrict__ W_out, u16* __restrict__ wt_out,
                            float2* __restrict__ rope_tab) {
  __shared__ float tile[32][33];
  const int blk = blockIdx.x, tid = threadIdx.x;
  if (blk < 4096) {                       // query fp32 -> bf16
    int i = blk * 256 + tid;
    float4 v = ((const float4*)query)[i];
    ushort4 o;
    o.x = f2bf(v.x); o.y = f2bf(v.y); o.z = f2bf(v.z); o.w = f2bf(v.w);
    ((ushort4*)q_bf)[i] = o;
  } else if (blk < 8192) {                // W transpose+convert (32x32 tiles)
    const float* W; u16* Wt; int N, t;
    if (blk < 7168) { W = W_qkv; Wt = wt_qkv; N = NQKV; t = blk - 4096; }
    else            { W = W_out; Wt = wt_out; N = D_MODEL; t = blk - 7168; }
    int nb = N / 32;
    int c0 = (t % nb) * 32, r0 = (t / nb) * 32;
    int tx = tid & 31, ty = tid >> 5;
    for (int i = ty; i < 32; i += 8)
      tile[i][tx] = W[(size_t)(r0 + i) * N + c0 + tx];
    __syncthreads();
    for (int i = ty; i < 32; i += 8)
      Wt[(size_t)(c0 + i) * KDIM + r0 + tx] = f2bf(tile[tx][i]);
  } else {                                // rope table: tab[f*2048+s] = (cos, sin)
    int i = (blk - 8192) * 256 + tid;     // 65536 entries
    int f = i >> 11, s = i & 2047;
    float inv = __expf(-(float)f * 0.28782313662425572f);  // ln(1e4)/32
    float ang = (float)s * inv;
    rope_tab[i] = make_float2(cosf(ang), sinf(ang));
  }
}

// ---------------- QKV GEMM + bias + RoPE + packed-store scatter ----------------
// `which` is BLOCK-uniform (blocks 0-7=q, 8-15=k, 16-23=v). Branch wraps the
// ENTIRE K-loop+epilogue (two disjoint register regions, max not union — the
// R8 in-loop branch bloated VGPR 100->144 and cost 12 us).
// q/k blocks: swapped mfma(B,A) -> lane holds 4 consecutive hd at fixed s ->
// packed 8B stores, no LDS transpose. v blocks: original order -> 4 consecutive
// s at fixed hd -> packed v^T stores. All staging XOR-swizzled (0 conflicts).
__global__ __launch_bounds__(256) void qkv_gemm_kernel(
    const u16* __restrict__ A, const u16* __restrict__ Bt, const float* __restrict__ bias,
    const float2* __restrict__ rope_tab,
    u16* __restrict__ qb, u16* __restrict__ kb, u16* __restrict__ vtb) {
  __shared__ u16 As[8192];
  __shared__ u16 Bs[8192];
  const int tid = threadIdx.x;
  const int lane = tid & 63, wave = tid >> 6;
  const int wr = (wave >> 1) << 6, wc = (wave & 1) << 6;
  const int lrow = lane & 15, quad = lane >> 4;
  const int sw = lrow & 7;
  const int rowA0 = blockIdx.y * 128, rowB0 = blockIdx.x * 128;

  const int which = rowB0 >> 10;         // block-uniform: 0=q 1=k 2=v
  const int col0 = rowB0 + wc;
  const int h = (col0 & 1023) >> 6;
  const int b = rowA0 >> 11;
  const int sbase = (rowA0 & 2047) + wr;

  f32x4 acc[4][4] = {};

  if (which < 2) {
    // ---------------- q/k path: swapped operands ----------------
    for (int k0 = 0; k0 < KDIM; k0 += 64) {
      __syncthreads();
#pragma unroll
      for (int it = 0; it < 4; ++it) {
        int flat = it * 256 + tid;
        int r = flat >> 3, cs = ((flat & 7) ^ (r & 7)) << 3;
        gload16(A + (size_t)(rowA0 + r) * KDIM + k0 + cs, As + flat * 8);
        gload16(Bt + (size_t)(rowB0 + r) * KDIM + k0 + cs, Bs + flat * 8);
      }
      __syncthreads();
#pragma unroll
      for (int kk = 0; kk < 64; kk += 32) {
        const int ch = ((kk >> 3) + quad) ^ sw;
        bf16x8 af[4], bfr[4];
#pragma unroll
        for (int mi = 0; mi < 4; ++mi)
          af[mi] = *(const bf16x8*)(As + (wr + mi * 16 + lrow) * 64 + (ch << 3));
#pragma unroll
        for (int ni = 0; ni < 4; ++ni)
          bfr[ni] = *(const bf16x8*)(Bs + (wc + ni * 16 + lrow) * 64 + (ch << 3));
#pragma unroll
        for (int mi = 0; mi < 4; ++mi)
#pragma unroll
          for (int ni = 0; ni < 4; ++ni)
            acc[mi][ni] = __builtin_amdgcn_mfma_f32_16x16x32_bf16(bfr[ni], af[mi], acc[mi][ni], 0, 0, 0);
      }
    }
    // epilogue: lane&15 <-> s, quad*4+r <-> channel
#pragma unroll
    for (int ni = 0; ni < 4; ++ni) {
      float4 bv = *(const float4*)&bias[col0 + ni * 16 + quad * 4];
#pragma unroll
      for (int mi = 0; mi < 4; ++mi) {
        acc[mi][ni][0] += bv.x; acc[mi][ni][1] += bv.y;
        acc[mi][ni][2] += bv.z; acc[mi][ni][3] += bv.w;
      }
    }
    const float qs = (which == 0) ? 0.18033688011112042f : 1.0f;
#pragma unroll
    for (int p = 0; p < 2; ++p) {
#pragma unroll
      for (int r = 0; r < 4; ++r) {
        const float2* tb = rope_tab + (size_t)(p * 16 + quad * 4 + r) * 2048;
#pragma unroll
        for (int mi = 0; mi < 4; ++mi) {
          float2 cs = tb[sbase + mi * 16 + lrow];
          float x1 = acc[mi][p][r], x2 = acc[mi][p + 2][r];
          acc[mi][p][r]     = (x1 * cs.x - x2 * cs.y) * qs;
          acc[mi][p + 2][r] = (x2 * cs.x + x1 * cs.y) * qs;
        }
      }
    }
    u16* dst = ((which == 0) ? qb : kb) + (size_t)(b * NH + h) * SEQ * HD;
#pragma unroll
    for (int mi = 0; mi < 4; ++mi) {
      size_t srow = (size_t)(sbase + mi * 16 + lrow) * HD + quad * 4;
#pragma unroll
      for (int ni = 0; ni < 4; ++ni) {
        ushort4 pk = packu4(acc[mi][ni][0], acc[mi][ni][1], acc[mi][ni][2], acc[mi][ni][3]);
        *(ushort4*)(dst + srow + ni * 16) = pk;
      }
    }
  } else {
    // ---------------- v path: original operand order ----------------
    for (int k0 = 0; k0 < KDIM; k0 += 64) {
      __syncthreads();
#pragma unroll
      for (int it = 0; it < 4; ++it) {
        int flat = it * 256 + tid;
        int r = flat >> 3, cs = ((flat & 7) ^ (r & 7)) << 3;
        gload16(A + (size_t)(rowA0 + r) * KDIM + k0 + cs, As + flat * 8);
        gload16(Bt + (size_t)(rowB0 + r) * KDIM + k0 + cs, Bs + flat * 8);
      }
      __syncthreads();
#pragma unroll
      for (int kk = 0; kk < 64; kk += 32) {
        const int ch = ((kk >> 3) + quad) ^ sw;
        bf16x8 af[4], bfr[4];
#pragma unroll
        for (int mi = 0; mi < 4; ++mi)
          af[mi] = *(const bf16x8*)(As + (wr + mi * 16 + lrow) * 64 + (ch << 3));
#pragma unroll
        for (int ni = 0; ni < 4; ++ni)
          bfr[ni] = *(const bf16x8*)(Bs + (wc + ni * 16 + lrow) * 64 + (ch << 3));
#pragma unroll
        for (int mi = 0; mi < 4; ++mi)
#pragma unroll
          for (int ni = 0; ni < 4; ++ni)
            acc[mi][ni] = __builtin_amdgcn_mfma_f32_16x16x32_bf16(af[mi], bfr[ni], acc[mi][ni], 0, 0, 0);
      }
    }
    // epilogue: lane&15 <-> channel(hd), quad*4+r <-> s -> packed v^T stores
#pragma unroll
    for (int ni = 0; ni < 4; ++ni) {
      float bv = bias[col0 + ni * 16 + lrow];
#pragma unroll
      for (int mi = 0; mi < 4; ++mi)
#pragma unroll
        for (int r = 0; r < 4; ++r) acc[mi][ni][r] += bv;
    }
    u16* dst = vtb + (size_t)(b * NH + h) * HD * SEQ;
#pragma unroll
    for (int ni = 0; ni < 4; ++ni) {
      int hd = ni * 16 + lrow;
#pragma unroll
      for (int mi = 0; mi < 4; ++mi) {
        ushort4 pk = packu4(acc[mi][ni][0], acc[mi][ni][1], acc[mi][ni][2], acc[mi][ni][3]);
        *(ushort4*)(dst + (size_t)hd * SEQ + sbase + mi * 16 + quad * 4) = pk;
      }
    }
  }
}

// ---------------- causal flash attention v7: 128q x 128k, CU-balanced ------
// 512 blocks; id->tile mapping pairs heavy+light on each CU (t1+t2=15 ->
// exactly 17 iterations per CU with 2 blocks/CU round-robin). Wave owns 32 q
// (groups lrow, lrow+16); K/V fragments read once feed both groups. Fixed-offset
// softmax (-12 folded into MFMA C-init; cancels in O = sum(p v)/sum(p)).
__global__ __launch_bounds__(256, 2) void flash_kernel(
    const u16* __restrict__ qb, const u16* __restrict__ kb,
    const u16* __restrict__ vtb, u16* __restrict__ attnb) {
  __shared__ u16 Ks[2][128 * 64];      // 32 KB (key-major, chunk^row swizzle)
  __shared__ u16 Vts[2][64 * 128];     // 32 KB (hd-major,  chunk^row swizzle)

  const int tid = threadIdx.x, lane = tid & 63, wave = tid >> 6;
  const int lrow = lane & 15, quad = lane >> 4;
  const int id = blockIdx.x;
  // CU-balance: first 256 blocks t=15..8 (heavy), last 256 t=0..7 -> pair sum 15
  const int t = (id < 256) ? (15 - (id >> 5)) : ((id >> 5) - 8);
  const int bh = id & 31;
  const int b = bh >> 4, h = bh & 15;

  const u16* qp = qb + (size_t)bh * SEQ * HD;
  const u16* kp = kb + (size_t)bh * SEQ * HD;
  const u16* vp = vtb + (size_t)bh * HD * SEQ;

  const int qa = t * 128 + wave * 32 + lrow;    // q-group a
  const int qg2 = qa + 16;                      // q-group b
  bf16x8 bqa[2], bqb[2];
#pragma unroll
  for (int hc = 0; hc < 2; ++hc) {
    bqa[hc] = *(const bf16x8*)(qp + (size_t)qa * HD + hc * 32 + quad * 8);
    bqb[hc] = *(const bf16x8*)(qp + (size_t)qg2 * HD + hc * 32 + quad * 8);
  }

#pragma unroll
  for (int it = 0; it < 4; ++it) {     // stage K/V tile 0 into buf 0
    int f = it * 256 + tid;
    int rk = f >> 3, ck = f & 7;
    gload16(kp + (size_t)rk * HD + ((ck ^ (rk & 7)) << 3), Ks[0] + f * 8);
    int rv = f >> 4, cv = f & 15;
    gload16(vp + (size_t)rv * SEQ + ((cv ^ (rv & 7)) << 3), Vts[0] + f * 8);
  }

  f32x4 oa[4] = {}, ob[4] = {};
  f32x4 la = {}, lb = {};
  const int sw = lrow & 7;

  for (int kt = 0; kt <= t; ++kt) {
    const int cur = kt & 1, nxt = cur ^ 1;
    __syncthreads();                   // drains cur staging; guards LDS reuse
    if (kt < t) {                      // async prefetch next 128-key tile
#pragma unroll
      for (int it = 0; it < 4; ++it) {
        int f = it * 256 + tid;
        int rk = f >> 3, ck = f & 7;
        gload16(kp + (size_t)((kt + 1) * 128 + rk) * HD + ((ck ^ (rk & 7)) << 3),
                Ks[nxt] + f * 8);
        int rv = f >> 4, cv = f & 15;
        gload16(vp + (size_t)rv * SEQ + (kt + 1) * 128 + ((cv ^ (rv & 7)) << 3),
                Vts[nxt] + f * 8);
      }
    }

    // S^T = K.Q^T, C-init = -12 (exp2 offset). Shared ak feeds both q-groups.
    f32x4 sa[8], sb[8];
#pragma unroll
    for (int ki = 0; ki < 8; ++ki) { sa[ki] = -12.f; sb[ki] = -12.f; }
#pragma unroll
    for (int hc = 0; hc < 2; ++hc) {
      bf16x8 ak[8];
#pragma unroll
      for (int ki = 0; ki < 8; ++ki)
        ak[ki] = *(const bf16x8*)(Ks[cur] + (ki * 16 + lrow) * 64 +
                                  (((hc * 4 + quad) ^ sw) << 3));
#pragma unroll
      for (int ki = 0; ki < 8; ++ki)
        sa[ki] = __builtin_amdgcn_mfma_f32_16x16x32_bf16(ak[ki], bqa[hc], sa[ki], 0, 0, 0);
#pragma unroll
      for (int ki = 0; ki < 8; ++ki)
        sb[ki] = __builtin_amdgcn_mfma_f32_16x16x32_bf16(ak[ki], bqb[hc], sb[ki], 0, 0, 0);
    }

    if (kt == t) {                     // causal mask (diagonal tile only)
#pragma unroll
      for (int ki = 0; ki < 8; ++ki)
#pragma unroll
        for (int r = 0; r < 4; ++r) {
          int key = kt * 128 + ki * 16 + quad * 4 + r;
          if (key > qa)  sa[ki][r] = -1e30f;
          if (key > qg2) sb[ki][r] = -1e30f;
        }
    }

    // exp2 (offset already applied) + vector denominator + packed P fragments
    bf16x4 pfa[8], pfb[8];
#pragma unroll
    for (int ki = 0; ki < 8; ++ki) {
#pragma unroll
      for (int r = 0; r < 4; ++r) { sa[ki][r] = exp2f(sa[ki][r]); sb[ki][r] = exp2f(sb[ki][r]); }
      la += sa[ki];
      lb += sb[ki];
      pfa[ki] = pack4(sa[ki][0], sa[ki][1], sa[ki][2], sa[ki][3]);
      pfb[ki] = pack4(sb[ki][0], sb[ki][1], sb[ki][2], sb[ki][3]);
    }

    // O^T += V^T.P^T — shared av feeds both q-groups
#pragma unroll
    for (int mi = 0; mi < 4; ++mi) {
      int vrow = (mi * 16 + lrow) * 128;
#pragma unroll
      for (int ki = 0; ki < 8; ++ki) {
        bf16x4 av = *(const bf16x4*)(Vts[cur] + vrow +
                                     ((((ki * 2 + (quad >> 1)) ^ sw) << 3) | ((quad & 1) << 2)));
        oa[mi] = mfma16(av, pfa[ki], oa[mi]);
        ob[mi] = mfma16(av, pfb[ki], ob[mi]);
      }
    }
  }

  // denominators: horizontal f32x4 sum, then cross-quad reduce
  float l_a = la[0] + la[1] + la[2] + la[3];
  float l_b = lb[0] + lb[1] + lb[2] + lb[3];
  l_a += __shfl_xor(l_a, 16); l_a += __shfl_xor(l_a, 32);
  l_b += __shfl_xor(l_b, 16); l_b += __shfl_xor(l_b, 32);
  float ra = 1.f / l_a, rb = 1.f / l_b;

  u16* opa = attnb + ((size_t)(b * SEQ + qa)) * D_MODEL + h * HD;
  u16* opb = attnb + ((size_t)(b * SEQ + qg2)) * D_MODEL + h * HD;
#pragma unroll
  for (int mi = 0; mi < 4; ++mi) {
    ushort4 pka = packu4(oa[mi][0] * ra, oa[mi][1] * ra, oa[mi][2] * ra, oa[mi][3] * ra);
    *(ushort4*)(opa + mi * 16 + quad * 4) = pka;
    ushort4 pkb = packu4(ob[mi][0] * rb, ob[mi][1] * rb, ob[mi][2] * rb, ob[mi][3] * rb);
    *(ushort4*)(opb + mi * 16 + quad * 4) = pkb;
  }
}

// -------- output projection: 128x64 tiles, swapped operands -> float4 stores ----
__global__ __launch_bounds__(256) void out_gemm_kernel(
    const u16* __restrict__ A, const u16* __restrict__ Bt, const float* __restrict__ bias,
    float* __restrict__ out) {
  __shared__ u16 As[128 * 64];
  __shared__ u16 Bs[64 * 64];
  const int tid = threadIdx.x;
  const int lane = tid & 63, wave = tid >> 6;
  const int lrow = lane & 15, quad = lane >> 4;
  const int sw = lrow & 7;
  const int wr = wave * 32;
  const int rowA0 = blockIdx.y * 128, colB0 = blockIdx.x * 64;

  f32x4 acc[2][4] = {};

  for (int k0 = 0; k0 < KDIM; k0 += 64) {
    __syncthreads();
#pragma unroll
    for (int it = 0; it < 4; ++it) {
      int f = it * 256 + tid;
      int r = f >> 3, cs = ((f & 7) ^ (r & 7)) << 3;
      gload16(A + (size_t)(rowA0 + r) * KDIM + k0 + cs, As + f * 8);
    }
#pragma unroll
    for (int it = 0; it < 2; ++it) {
      int f = it * 256 + tid;
      int r = f >> 3, cs = ((f & 7) ^ (r & 7)) << 3;
      gload16(Bt + (size_t)(colB0 + r) * KDIM + k0 + cs, Bs + f * 8);
    }
    __syncthreads();
#pragma unroll
    for (int kk = 0; kk < 64; kk += 32) {
      const int ch = ((kk >> 3) + quad) ^ sw;
      bf16x8 af[2], bfr[4];
#pragma unroll
      for (int mi = 0; mi < 2; ++mi)
        af[mi] = *(const bf16x8*)(As + (wr + mi * 16 + lrow) * 64 + (ch << 3));
#pragma unroll
      for (int ni = 0; ni < 4; ++ni)
        bfr[ni] = *(const bf16x8*)(Bs + (ni * 16 + lrow) * 64 + (ch << 3));
      // swapped operands: lane&15 <-> A-row (s), quad*4+r <-> B-row (col)
#pragma unroll
      for (int mi = 0; mi < 2; ++mi)
#pragma unroll
        for (int ni = 0; ni < 4; ++ni)
          acc[mi][ni] = __builtin_amdgcn_mfma_f32_16x16x32_bf16(bfr[ni], af[mi], acc[mi][ni], 0, 0, 0);
    }
  }

#pragma unroll
  for (int ni = 0; ni < 4; ++ni) {
    float4 bv = *(const float4*)&bias[colB0 + ni * 16 + quad * 4];
#pragma unroll
    for (int mi = 0; mi < 2; ++mi) {
      int row = rowA0 + wr + mi * 16 + lrow;
      float4 o4 = make_float4(acc[mi][ni][0] + bv.x, acc[mi][ni][1] + bv.y,
                              acc[mi][ni][2] + bv.z, acc[mi][ni][3] + bv.w);
      *(float4*)&out[(size_t)row * D_MODEL + colB0 + ni * 16 + quad * 4] = o4;
    }
  }
}

extern "C" void kernel_launch(void* const* d_in, const int* in_sizes, int n_in,
                              void* d_out, int out_size, void* d_ws, size_t ws_size,
                              hipStream_t stream) {
  const float* query = (const float*)d_in[0];
  const float* W_qkv = (const float*)d_in[1];
  const float* b_qkv = (const float*)d_in[2];
  const float* W_out = (const float*)d_in[3];
  const float* b_out = (const float*)d_in[4];
  float* out = (float*)d_out;

  char* ws = (char*)d_ws;
  u16* q_bf    = (u16*)(ws);                 //  8 MB  query bf16 (4096x1024)
  u16* wt_qkv  = (u16*)(ws + 8388608);       //  6 MB  W_qkv^T bf16
  u16* wt_out  = (u16*)(ws + 14680064);      //  2 MB  W_out^T bf16
  u16* qbuf    = (u16*)(ws + 16777216);      //  8 MB  q (bh,s,hd) plain, pre-scaled kS
  u16* kbuf    = (u16*)(ws + 25165824);      //  8 MB  k (bh,s,hd) plain
  u16* vtbuf   = (u16*)(ws + 33554432);      //  8 MB  v^T (bh,hd,s) plain
  u16* attnb   = (u16*)(ws + 41943040);      //  8 MB  attn (B,S,D) bf16
  float2* rope = (float2*)(ws + 50331648);   // 512 KB rope table [f][s]

  prep_kernel<<<dim3(8448), dim3(256), 0, stream>>>(query, q_bf, W_qkv, wt_qkv,
                                                    W_out, wt_out, rope);
  qkv_gemm_kernel<<<dim3(NQKV / 128, ROWS / 128), dim3(256), 0, stream>>>(
      q_bf, wt_qkv, b_qkv, rope, qbuf, kbuf, vtbuf);
  flash_kernel<<<dim3(512), dim3(256), 0, stream>>>(qbuf, kbuf, vtbuf, attnb);
  out_gemm_kernel<<<dim3(D_MODEL / 64, ROWS / 128), dim3(256), 0, stream>>>(
      attnb, wt_out, b_out, out);
}